// Round 2
// baseline (295.875 us; speedup 1.0000x reference)
//
#include <hip/hip_runtime.h>
#include <cfloat>

// VectorQuantizer: inputs [65536,64] f32, embeddings [2048,64] f32
#define N_TOTAL 65536
#define DIM     64
#define NEMB    2048
#define BM      128       // rows per block
#define BK      128       // embeddings per K-tile
#define XSTRIDE 132       // Xs (transposed [d][r]) row stride: mult-of-4, spreads write banks
#define ESTRIDE 68        // Es (natural [k][d]) row stride: 64+4, spreads read banks

// ---------------------------------------------------------------------------
// Kernel 1: per-embedding squared norms -> d_ws (2048 floats)
// ---------------------------------------------------------------------------
__global__ void enorm_kernel(const float* __restrict__ emb, float* __restrict__ enorm) {
    int k = blockIdx.x * blockDim.x + threadIdx.x;
    const float4* row = (const float4*)(emb + (size_t)k * DIM);
    float s = 0.f;
#pragma unroll
    for (int i = 0; i < DIM / 4; ++i) {
        float4 v = row[i];
        s = fmaf(v.x, v.x, s);
        s = fmaf(v.y, v.y, s);
        s = fmaf(v.z, v.z, s);
        s = fmaf(v.w, v.w, s);
    }
    enorm[k] = s;
}

// ---------------------------------------------------------------------------
// Kernel 2: main VQ.
//   q(row,k) = dot(x_row, e_k) - ||e_k||^2/2 ; argmin dist == argmax q.
// 256 threads = (ty 0..15) x (tx 0..15); thread tile 8 rows x 8 cols.
//   rows: ty*8 + i ; cols: tx + 16*j  (j 0..7, ascending col for tie-break)
// Xs transposed [d][r] (stride 132): x-fragment reads are 4-addr broadcast,
//   conflict-free. Staged once via scalar scatter (8-way conflict, once per
//   block = noise) fused with the flat_inputs copy.
// Es natural [k][d] (stride 68): staged with direct float4 writes, bank =
//   4*(r+c4) mod 32 -> conflict-free. Fragment reads Es[tx+16j][d0..d0+3]:
//   bank = (4tx+d0) mod 32 -> 2-way (free) + 4-lane broadcast.
// ---------------------------------------------------------------------------
__global__ __launch_bounds__(256, 2) void vq_main_kernel(
        const float* __restrict__ x,
        const float* __restrict__ emb,
        const float* __restrict__ enorm,
        float* __restrict__ quant,
        float* __restrict__ idx_out,
        float* __restrict__ flat) {

    __shared__ float Xs[DIM][XSTRIDE];
    __shared__ float Es[BK][ESTRIDE];

    const int t    = threadIdx.x;
    const int tx   = t & 15;
    const int ty   = t >> 4;
    const int row0 = blockIdx.x * BM;

    // ---- stage X tile (transposed) + fused flat_inputs copy ----
    {
        const int c4 = t & 15;   // float4 index along D
        const int rr = t >> 4;   // row within pass
#pragma unroll
        for (int p = 0; p < BM; p += 16) {
            const int r = p + rr;
            const size_t off = (size_t)(row0 + r) * DIM + c4 * 4;
            float4 v = *(const float4*)(x + off);
            *(float4*)(flat + off) = v;          // flat_inputs output
            Xs[c4 * 4 + 0][r] = v.x;
            Xs[c4 * 4 + 1][r] = v.y;
            Xs[c4 * 4 + 2][r] = v.z;
            Xs[c4 * 4 + 3][r] = v.w;
        }
    }

    float best[8];
    int   besti[8];
#pragma unroll
    for (int i = 0; i < 8; ++i) { best[i] = -FLT_MAX; besti[i] = 0; }

    for (int kt = 0; kt < NEMB / BK; ++kt) {
        // en loads issued before the barrier: staging hides their latency
        float en[8];
#pragma unroll
        for (int j = 0; j < 8; ++j)
            en[j] = enorm[kt * BK + tx + 16 * j];

        __syncthreads();   // previous tile's readers done with Es (also covers Xs on kt=0)
        {
            const int c4 = t & 15;
            const int rr = t >> 4;
#pragma unroll
            for (int p = 0; p < BK; p += 16) {
                const int r = p + rr;
                float4 v = *(const float4*)(emb + (size_t)(kt * BK + r) * DIM + c4 * 4);
                *(float4*)&Es[r][c4 * 4] = v;    // conflict-free b128 write
            }
        }
        __syncthreads();

        float acc[8][8];
#pragma unroll
        for (int i = 0; i < 8; ++i)
#pragma unroll
            for (int j = 0; j < 8; ++j) acc[i][j] = -0.5f * en[j];

#pragma unroll 2
        for (int d0 = 0; d0 < DIM; d0 += 4) {
            float e[8][4];
#pragma unroll
            for (int j = 0; j < 8; ++j) {
                float4 v = *(const float4*)&Es[tx + 16 * j][d0];
                e[j][0] = v.x; e[j][1] = v.y; e[j][2] = v.z; e[j][3] = v.w;
            }
#pragma unroll
            for (int dd = 0; dd < 4; ++dd) {
                float4 xa = *(const float4*)&Xs[d0 + dd][ty * 8];
                float4 xb = *(const float4*)&Xs[d0 + dd][ty * 8 + 4];
                float xs[8] = {xa.x, xa.y, xa.z, xa.w, xb.x, xb.y, xb.z, xb.w};
#pragma unroll
                for (int i = 0; i < 8; ++i)
#pragma unroll
                    for (int j = 0; j < 8; ++j)
                        acc[i][j] = fmaf(xs[i], e[j][dd], acc[i][j]);
            }
        }

        // running argmax of q (cols ascending in j => first-min tie-break)
#pragma unroll
        for (int i = 0; i < 8; ++i) {
#pragma unroll
            for (int j = 0; j < 8; ++j) {
                if (acc[i][j] > best[i]) {
                    best[i]  = acc[i][j];
                    besti[i] = kt * BK + tx + 16 * j;
                }
            }
        }
    }

    // ---- butterfly-merge across the 16 tx lanes sharing each row group ----
#pragma unroll
    for (int m = 1; m < 16; m <<= 1) {
#pragma unroll
        for (int i = 0; i < 8; ++i) {
            float ob = __shfl_xor(best[i], m, 64);
            int   oi = __shfl_xor(besti[i], m, 64);
            if (ob > best[i] || (ob == best[i] && oi < besti[i])) {
                best[i] = ob; besti[i] = oi;
            }
        }
    }

    // ---- write indices (as float) ----
    if (tx == 0) {
#pragma unroll
        for (int i = 0; i < 8; ++i)
            idx_out[row0 + ty * 8 + i] = (float)besti[i];
    }

    // ---- write quantized = embeddings[besti] (16 lanes x float4 per row) ----
#pragma unroll
    for (int i = 0; i < 8; ++i) {
        float4 v = *(const float4*)(emb + (size_t)besti[i] * DIM + tx * 4);
        *(float4*)(quant + (size_t)(row0 + ty * 8 + i) * DIM + tx * 4) = v;
    }
}

extern "C" void kernel_launch(void* const* d_in, const int* in_sizes, int n_in,
                              void* d_out, int out_size, void* d_ws, size_t ws_size,
                              hipStream_t stream) {
    const float* x   = (const float*)d_in[0];   // [65536, 64]
    const float* emb = (const float*)d_in[1];   // [2048, 64]
    float* out   = (float*)d_out;
    float* quant = out;                               // 4194304 floats
    float* idxf  = out + (size_t)N_TOTAL * DIM;       // 65536 floats
    float* flat  = idxf + N_TOTAL;                    // 4194304 floats
    float* enorm = (float*)d_ws;                      // 2048 floats scratch

    enorm_kernel<<<NEMB / 256, 256, 0, stream>>>(emb, enorm);
    vq_main_kernel<<<N_TOTAL / BM, 256, 0, stream>>>(x, emb, enorm, quant, idxf, flat);
}

// Round 3
// 149.908 us; speedup vs baseline: 1.9737x; 1.9737x over previous
//
#include <hip/hip_runtime.h>
#include <cfloat>

// VectorQuantizer: inputs [65536,64] f32, embeddings [2048,64] f32
#define N_TOTAL 65536
#define DIM     64
#define NEMB    2048
#define ESTRIDE 72    // ushort stride per code-row in LDS (64 + 8: bank-balanced, keeps 16B align)

typedef __attribute__((ext_vector_type(8))) short  short8;   // 8 bf16 = 4 VGPRs (MFMA A/B frag)
typedef __attribute__((ext_vector_type(4))) float  floatx4;  // MFMA C/D frag

__device__ __forceinline__ ushort f2bf(float f) {            // fp32 -> bf16 RNE
    unsigned u = __float_as_uint(f);
    u += 0x7FFFu + ((u >> 16) & 1u);
    return (ushort)(u >> 16);
}
__device__ __forceinline__ float bf2f(ushort h) { return __uint_as_float(((unsigned)h) << 16); }

// ---------------------------------------------------------------------------
// Prep: split embeddings into bf16 limbs (eh + el ~ e to ~16-bit mantissa)
// and compute fp32 norms. 2048 rows x 4 lanes/row.
// ---------------------------------------------------------------------------
__global__ void prep_kernel(const float* __restrict__ emb, ushort* __restrict__ eh,
                            ushort* __restrict__ el, float* __restrict__ en) {
    int t = blockIdx.x * 256 + threadIdx.x;   // 8192 threads
    int row = t >> 2, c = (t & 3) * 16;
    const float* src = emb + row * DIM + c;
    float s = 0.f;
    ushort hbuf[16], lbuf[16];
#pragma unroll
    for (int i = 0; i < 16; ++i) {
        float v = src[i];
        ushort hh = f2bf(v);
        hbuf[i] = hh;
        lbuf[i] = f2bf(v - bf2f(hh));
        s = fmaf(v, v, s);
    }
#pragma unroll
    for (int i = 0; i < 2; ++i) {
        ((uint4*)(eh + row * DIM + c))[i] = ((const uint4*)hbuf)[i];
        ((uint4*)(el + row * DIM + c))[i] = ((const uint4*)lbuf)[i];
    }
    s += __shfl_xor(s, 1, 64);
    s += __shfl_xor(s, 2, 64);
    if ((t & 3) == 0) en[row] = s;
}

// ---------------------------------------------------------------------------
// Main: q(row,k) = x.e - ||e||^2/2 (argmax == argmin dist) via 3-term
// split-bf16 MFMA (xh*eh + xh*el + xl*eh); per-lane top-2 with pairwise
// pre-max; butterfly merge; exact fp32 rescore of both candidates.
// Wave = 32 rows (two 16x16 M-tiles sharing B-frags). Block = 4 waves = 128
// rows. A-frags in registers for the whole K sweep; codes streamed through
// LDS in 128-col super-tiles.
// ---------------------------------------------------------------------------
__global__ __launch_bounds__(256, 2) void vq_mfma_kernel(
        const float* __restrict__ x, const float* __restrict__ emb,
        const ushort* __restrict__ ehg, const ushort* __restrict__ elg,
        const float* __restrict__ eng,
        float* __restrict__ quant, float* __restrict__ idxf, float* __restrict__ flat) {

    __shared__ ushort EhS[128 * ESTRIDE];
    __shared__ ushort ElS[128 * ESTRIDE];
    __shared__ float  EnS[128];

    const int t = threadIdx.x;
    const int wave = t >> 6, lane = t & 63;
    const int n = lane & 15, q = lane >> 4;          // frag col-lane / quad
    const int brow0 = blockIdx.x * 128;
    const int row0  = brow0 + wave * 32;

    // ---- flat_inputs copy (block-coalesced float4) ----
    {
        const float4* s4 = (const float4*)(x + (size_t)brow0 * DIM);
        float4*       d4 = (float4*)(flat + (size_t)brow0 * DIM);
#pragma unroll
        for (int i = 0; i < 8; ++i) d4[i * 256 + t] = s4[i * 256 + t];
    }

    // ---- A fragments: [tile][kstep], limbs hi/lo. A[m=lane&15][k=q*8+j]. ----
    short8 ah[2][2], al[2][2];
#pragma unroll
    for (int tl = 0; tl < 2; ++tl) {
        const float* xr = x + (size_t)(row0 + tl * 16 + n) * DIM;
#pragma unroll
        for (int ks = 0; ks < 2; ++ks) {
            const float* p = xr + ks * 32 + q * 8;
            float4 v0 = *(const float4*)p, v1 = *(const float4*)(p + 4);
            float xv[8] = {v0.x, v0.y, v0.z, v0.w, v1.x, v1.y, v1.z, v1.w};
#pragma unroll
            for (int j = 0; j < 8; ++j) {
                ushort hh = f2bf(xv[j]);
                ah[tl][ks][j] = (short)hh;
                al[tl][ks][j] = (short)f2bf(xv[j] - bf2f(hh));
            }
        }
    }

    // top-2 state per lane row (8 rows: tile*4 + reg)
    float best[8], sec[8];
    int   bidx[8], sidx[8];
#pragma unroll
    for (int r = 0; r < 8; ++r) { best[r] = -FLT_MAX; sec[r] = -FLT_MAX; bidx[r] = 0; sidx[r] = 0; }

    float prev[8];
    int   prevc = 0;

    for (int st = 0; st < 16; ++st) {
        __syncthreads();
        {   // stage 128 cols x 64 bf16 per limb + norms
            const int col = t >> 1, half = t & 1;
            const size_t g = (size_t)(st * 128 + col) * DIM + half * 32;
            const uint4* sh = (const uint4*)(ehg + g);
            const uint4* sl = (const uint4*)(elg + g);
            uint4* dh = (uint4*)&EhS[col * ESTRIDE + half * 32];
            uint4* dl = (uint4*)&ElS[col * ESTRIDE + half * 32];
#pragma unroll
            for (int i = 0; i < 4; ++i) { dh[i] = sh[i]; dl[i] = sl[i]; }
            if (t < 128) EnS[t] = eng[st * 128 + t];
        }
        __syncthreads();

#pragma unroll 2
        for (int sub = 0; sub < 8; ++sub) {
            const int c0 = sub * 16;
            const float enh = -0.5f * EnS[c0 + n];
            floatx4 a0 = {enh, enh, enh, enh};
            floatx4 a1 = a0;
#pragma unroll
            for (int ks = 0; ks < 2; ++ks) {
                short8 bh = *(const short8*)&EhS[(c0 + n) * ESTRIDE + ks * 32 + q * 8];
                short8 bl = *(const short8*)&ElS[(c0 + n) * ESTRIDE + ks * 32 + q * 8];
                a0 = __builtin_amdgcn_mfma_f32_16x16x32_bf16(ah[0][ks], bh, a0, 0, 0, 0);
                a0 = __builtin_amdgcn_mfma_f32_16x16x32_bf16(ah[0][ks], bl, a0, 0, 0, 0);
                a0 = __builtin_amdgcn_mfma_f32_16x16x32_bf16(al[0][ks], bh, a0, 0, 0, 0);
                a1 = __builtin_amdgcn_mfma_f32_16x16x32_bf16(ah[1][ks], bh, a1, 0, 0, 0);
                a1 = __builtin_amdgcn_mfma_f32_16x16x32_bf16(ah[1][ks], bl, a1, 0, 0, 0);
                a1 = __builtin_amdgcn_mfma_f32_16x16x32_bf16(al[1][ks], bh, a1, 0, 0, 0);
            }
            const int col = st * 128 + c0 + n;
            if ((sub & 1) == 0) {
#pragma unroll
                for (int r = 0; r < 4; ++r) { prev[r] = a0[r]; prev[4 + r] = a1[r]; }
                prevc = col;
            } else {
#pragma unroll
                for (int r = 0; r < 8; ++r) {
                    float cv = (r < 4) ? a0[r & 3] : a1[r & 3];
                    bool  take = cv > prev[r];            // strict: tie keeps earlier col
                    float sw = take ? cv : prev[r];
                    int   cw = take ? col : prevc;
                    bool  b1 = sw > best[r];
                    bool  b2 = sw > sec[r];
                    sec[r]  = b1 ? best[r] : (b2 ? sw : sec[r]);
                    sidx[r] = b1 ? bidx[r] : (b2 ? cw : sidx[r]);
                    best[r] = b1 ? sw : best[r];
                    bidx[r] = b1 ? cw : bidx[r];
                }
            }
        }
    }

    // ---- butterfly top-2 merge across the 16 col-lanes of each q-group ----
#pragma unroll
    for (int mask = 1; mask < 16; mask <<= 1) {
#pragma unroll
        for (int r = 0; r < 8; ++r) {
            float ob  = __shfl_xor(best[r], mask, 64);
            int   obi = __shfl_xor(bidx[r], mask, 64);
            float os  = __shfl_xor(sec[r], mask, 64);
            int   osi = __shfl_xor(sidx[r], mask, 64);
            bool ow = ob > best[r] || (ob == best[r] && obi < bidx[r]);
            float nb = ow ? ob : best[r];  int nbi = ow ? obi : bidx[r];
            float lb = ow ? best[r] : ob;  int lbi = ow ? bidx[r] : obi;  // losing best
            bool sv = os > sec[r] || (os == sec[r] && osi < sidx[r]);
            float bs = sv ? os : sec[r];   int bsi = sv ? osi : sidx[r]; // better second
            bool s3 = lb > bs || (lb == bs && lbi < bsi);
            sec[r]  = s3 ? lb : bs;
            sidx[r] = s3 ? lbi : bsi;
            best[r] = nb;
            bidx[r] = nbi;
        }
    }

    // ---- exact fp32 rescore of both candidates + outputs ----
#pragma unroll
    for (int r = 0; r < 8; ++r) {
        const int tl = r >> 2;
        const int ra = row0 + tl * 16 + q * 4 + (r & 3);   // C row = q*4 + reg
        const int cA = bidx[r], cB = sidx[r];
        float4 xv = *(const float4*)(x   + (size_t)ra * DIM + n * 4);
        float4 ea = *(const float4*)(emb + (size_t)cA * DIM + n * 4);
        float4 eb = *(const float4*)(emb + (size_t)cB * DIM + n * 4);
        float pa = (xv.x - 0.5f * ea.x) * ea.x + (xv.y - 0.5f * ea.y) * ea.y
                 + (xv.z - 0.5f * ea.z) * ea.z + (xv.w - 0.5f * ea.w) * ea.w;
        float pb = (xv.x - 0.5f * eb.x) * eb.x + (xv.y - 0.5f * eb.y) * eb.y
                 + (xv.z - 0.5f * eb.z) * eb.z + (xv.w - 0.5f * eb.w) * eb.w;
#pragma unroll
        for (int mask = 1; mask < 16; mask <<= 1) {
            pa += __shfl_xor(pa, mask, 64);
            pb += __shfl_xor(pb, mask, 64);
        }
        bool useB = pb > pa || (pb == pa && cB < cA);
        int cw = useB ? cB : cA;
        float4 ew;
        ew.x = useB ? eb.x : ea.x; ew.y = useB ? eb.y : ea.y;
        ew.z = useB ? eb.z : ea.z; ew.w = useB ? eb.w : ea.w;
        *(float4*)(quant + (size_t)ra * DIM + n * 4) = ew;
        if (n == r) idxf[ra] = (float)cw;
    }
}

extern "C" void kernel_launch(void* const* d_in, const int* in_sizes, int n_in,
                              void* d_out, int out_size, void* d_ws, size_t ws_size,
                              hipStream_t stream) {
    const float* x   = (const float*)d_in[0];   // [65536, 64]
    const float* emb = (const float*)d_in[1];   // [2048, 64]
    float* out   = (float*)d_out;
    float* quant = out;                               // 4194304 floats
    float* idxf  = out + (size_t)N_TOTAL * DIM;       // 65536 floats
    float* flat  = idxf + N_TOTAL;                    // 4194304 floats

    ushort* eh = (ushort*)d_ws;                       // 2048*64 bf16
    ushort* el = eh + (size_t)NEMB * DIM;             // 2048*64 bf16
    float*  en = (float*)(el + (size_t)NEMB * DIM);   // 2048 f32  (total ws: 520 KB)

    prep_kernel<<<32, 256, 0, stream>>>(emb, eh, el, en);
    vq_mfma_kernel<<<N_TOTAL / 128, 256, 0, stream>>>(x, emb, eh, el, en, quant, idxf, flat);
}

// Round 4
// 127.055 us; speedup vs baseline: 2.3287x; 1.1799x over previous
//
#include <hip/hip_runtime.h>
#include <cfloat>

// VectorQuantizer: inputs [65536,64] f32, embeddings [2048,64] f32
#define N_TOTAL 65536
#define DIM     64
#define NEMB    2048

typedef __attribute__((ext_vector_type(8))) _Float16 half8;   // MFMA A/B frag (4 VGPRs)
typedef __attribute__((ext_vector_type(4))) float    floatx4; // MFMA C/D frag

// ---------------------------------------------------------------------------
// Prep: pack embeddings as f16 in MFMA-B frag-major layout
//   chunk c = (g*2 + ks)*64 + lane, lane = q*16 + n:
//   ehp[c] = e_f16[col = g*16+n][k = ks*32 + q*8 .. +8)
// so one supertile (4 groups x 2 ks) is 8 KB contiguous -> flat global_load_lds.
// Also fp32 norms -> en[2048].
// ---------------------------------------------------------------------------
__global__ void prep_kernel(const float* __restrict__ emb,
                            half8* __restrict__ ehp, float* __restrict__ en) {
    const int t = blockIdx.x * 256 + threadIdx.x;   // 16384 threads
    {
        const int l   = t & 63;
        const int ks  = (t >> 6) & 1;
        const int g   = t >> 7;
        const int col = g * 16 + (l & 15);
        const int kb  = ks * 32 + (l >> 4) * 8;
        const float* s = emb + col * DIM + kb;
        float4 v0 = *(const float4*)s, v1 = *(const float4*)(s + 4);
        half8 hv;
        hv[0] = (_Float16)v0.x; hv[1] = (_Float16)v0.y;
        hv[2] = (_Float16)v0.z; hv[3] = (_Float16)v0.w;
        hv[4] = (_Float16)v1.x; hv[5] = (_Float16)v1.y;
        hv[6] = (_Float16)v1.z; hv[7] = (_Float16)v1.w;
        ehp[t] = hv;
    }
    if (t < NEMB * 4) {
        const int row = t >> 2, seg = t & 3;
        const float* s = emb + row * DIM + seg * 16;
        float acc = 0.f;
#pragma unroll
        for (int i = 0; i < 4; ++i) {
            float4 v = ((const float4*)s)[i];
            acc = fmaf(v.x, v.x, acc); acc = fmaf(v.y, v.y, acc);
            acc = fmaf(v.z, v.z, acc); acc = fmaf(v.w, v.w, acc);
        }
        acc += __shfl_xor(acc, 1, 64);
        acc += __shfl_xor(acc, 2, 64);
        if (seg == 0) en[row] = acc;
    }
}

// ---------------------------------------------------------------------------
// Main. Block = 256 thr = 4 waves; block owns 64 rows. Wave pair (p) shares
// 32 rows; wave half (h) scans cols [h*1024, h*1024+1024). Each wave
// self-stages 64-col supertiles (8 KB, frag-major) into its private LDS
// region via global_load_lds -> NO barriers in the K-loop.
//   approx score q = x.eh - ||e||^2/2 + 128  (f16 2-limb x, 1-limb e)
//   packed key = (bits(q) & ~63) | (63 - L), L = st*4+sub  (per-lane col id)
//   branchless top-2: min/max/max. Epilogue: exact fp32 rescore of 4
//   candidates (top-2 per half), tie -> lower col.
// ---------------------------------------------------------------------------
__global__ __launch_bounds__(256, 4) void vq_mfma_kernel(
        const float* __restrict__ x, const float* __restrict__ emb,
        const uint4* __restrict__ ehp, const float* __restrict__ eng,
        float* __restrict__ quant, float* __restrict__ idxf,
        float* __restrict__ flat) {

    __shared__ uint4 Stage[4][512];   // 8 KB per wave
    __shared__ uint4 Mrg[2][64];      // [half][local row] = {bval,bcol,sval,scol}

    const int t    = threadIdx.x;
    const int wave = t >> 6, lane = t & 63;
    const int n = lane & 15, q = lane >> 4;
    const int h = wave & 1, p = wave >> 1;
    const int blk0 = blockIdx.x * 64;
    const int row0 = blk0 + p * 32;

    // ---- flat_inputs copy (block-coalesced) ----
    {
        const float4* s4 = (const float4*)(x + (size_t)blk0 * DIM);
        float4*       d4 = (float4*)(flat + (size_t)blk0 * DIM);
#pragma unroll
        for (int i = 0; i < 4; ++i) d4[i * 256 + t] = s4[i * 256 + t];
    }

    // ---- A fragments, f16 2-limb split. A[m=lane&15][k=q*8+j] ----
    half8 ah[2][2], al[2][2];
#pragma unroll
    for (int tl = 0; tl < 2; ++tl)
#pragma unroll
        for (int ks = 0; ks < 2; ++ks) {
            const float* pp = x + (size_t)(row0 + tl * 16 + n) * DIM + ks * 32 + q * 8;
            float4 v0 = *(const float4*)pp, v1 = *(const float4*)(pp + 4);
            float xv[8] = {v0.x, v0.y, v0.z, v0.w, v1.x, v1.y, v1.z, v1.w};
#pragma unroll
            for (int j = 0; j < 8; ++j) {
                _Float16 hh = (_Float16)xv[j];
                ah[tl][ks][j] = hh;
                al[tl][ks][j] = (_Float16)(xv[j] - (float)hh);
            }
        }

    unsigned best[8], sec[8];
#pragma unroll
    for (int r = 0; r < 8; ++r) { best[r] = 0u; sec[r] = 0u; }

    const char* ehb = (const char*)ehp;
    for (int st = 0; st < 16; ++st) {
        const int colbase = h * 1024 + st * 64;
        const int g0 = colbase >> 4;
        // in-flight ds_reads of the previous tile must retire before DMA overwrite
        asm volatile("s_waitcnt lgkmcnt(0)" ::: "memory");
#pragma unroll
        for (int i = 0; i < 8; ++i) {
            const unsigned* gp =
                (const unsigned*)(ehb + (size_t)g0 * 2048 + i * 1024 + lane * 16);
            __builtin_amdgcn_global_load_lds(
                (const __attribute__((address_space(1))) unsigned*)gp,
                (__attribute__((address_space(3))) unsigned*)&Stage[wave][i * 64],
                16, 0, 0);
        }
        float en4[4];
#pragma unroll
        for (int s = 0; s < 4; ++s) en4[s] = eng[colbase + s * 16 + n];
        asm volatile("s_waitcnt vmcnt(0)" ::: "memory");

#pragma unroll
        for (int sub = 0; sub < 4; ++sub) {
            const float enh = fmaf(-0.5f, en4[sub], 128.0f);
            floatx4 a0 = {enh, enh, enh, enh};
            floatx4 a1 = a0;
#pragma unroll
            for (int ks = 0; ks < 2; ++ks) {
                half8 b = *(const half8*)&Stage[wave][(sub * 2 + ks) * 64 + lane];
                a0 = __builtin_amdgcn_mfma_f32_16x16x32_f16(ah[0][ks], b, a0, 0, 0, 0);
                a0 = __builtin_amdgcn_mfma_f32_16x16x32_f16(al[0][ks], b, a0, 0, 0, 0);
                a1 = __builtin_amdgcn_mfma_f32_16x16x32_f16(ah[1][ks], b, a1, 0, 0, 0);
                a1 = __builtin_amdgcn_mfma_f32_16x16x32_f16(al[1][ks], b, a1, 0, 0, 0);
            }
            const unsigned Lp = (unsigned)(63 - (st * 4 + sub));
#pragma unroll
            for (int r = 0; r < 8; ++r) {
                float v = (r < 4) ? a0[r] : a1[r - 4];
                unsigned key = (__float_as_uint(v) & 0xFFFFFFC0u) | Lp;
                unsigned lo  = best[r] < key ? best[r] : key;
                best[r] = best[r] > key ? best[r] : key;
                sec[r]  = sec[r] > lo ? sec[r] : lo;
            }
        }
    }

    // ---- decode per-lane top-2 to (bucketed bits, full col) ----
    unsigned bval[8], bcol[8], sval[8], scol[8];
#pragma unroll
    for (int r = 0; r < 8; ++r) {
        bval[r] = best[r] & 0xFFFFFFC0u;
        bcol[r] = (unsigned)(h * 1024 + (63 - (int)(best[r] & 63u)) * 16 + n);
        sval[r] = sec[r] & 0xFFFFFFC0u;
        scol[r] = (unsigned)(h * 1024 + (63 - (int)(sec[r] & 63u)) * 16 + n);
    }
    // ---- butterfly top-2 merge across the 16 n-lanes of each q-group ----
#pragma unroll
    for (int m = 1; m < 16; m <<= 1) {
#pragma unroll
        for (int r = 0; r < 8; ++r) {
            unsigned ov  = (unsigned)__shfl_xor((int)bval[r], m, 64);
            unsigned oc  = (unsigned)__shfl_xor((int)bcol[r], m, 64);
            unsigned ov2 = (unsigned)__shfl_xor((int)sval[r], m, 64);
            unsigned oc2 = (unsigned)__shfl_xor((int)scol[r], m, 64);
            bool ow = (ov > bval[r]) || (ov == bval[r] && oc < bcol[r]);
            unsigned nbv = ow ? ov : bval[r], nbc = ow ? oc : bcol[r];
            unsigned lv  = ow ? bval[r] : ov, lc  = ow ? bcol[r] : oc;
            bool sv2 = (ov2 > sval[r]) || (ov2 == sval[r] && oc2 < scol[r]);
            unsigned bsv = sv2 ? ov2 : sval[r], bsc = sv2 ? oc2 : scol[r];
            bool s3 = (lv > bsv) || (lv == bsv && lc < bsc);
            sval[r] = s3 ? lv : bsv; scol[r] = s3 ? lc : bsc;
            bval[r] = nbv; bcol[r] = nbc;
        }
    }
    // ---- publish per-half candidates (rows: tl*16 + q*4 + r) ----
    if (n == 0) {
#pragma unroll
        for (int r = 0; r < 8; ++r) {
            const int lr = p * 32 + (r >> 2) * 16 + q * 4 + (r & 3);
            Mrg[h][lr] = make_uint4(bval[r], bcol[r], sval[r], scol[r]);
        }
    }
    __syncthreads();

    // ---- exact fp32 rescore of 4 candidates; wave w handles 16 rows ----
#pragma unroll
    for (int r = 0; r < 4; ++r) {
        const int lr   = wave * 16 + q * 4 + r;
        const int grow = blk0 + lr;
        uint4 c0v = Mrg[0][lr], c1v = Mrg[1][lr];
        int cand[4] = {(int)c0v.y, (int)c0v.w, (int)c1v.y, (int)c1v.w};
        float4 xv = *(const float4*)(x + (size_t)grow * DIM + n * 4);
        float pbest = -FLT_MAX; int cbest = 0;
        float4 ebest = {0.f, 0.f, 0.f, 0.f};
#pragma unroll
        for (int c = 0; c < 4; ++c) {
            float4 e = *(const float4*)(emb + (size_t)cand[c] * DIM + n * 4);
            float pp = (xv.x - 0.5f * e.x) * e.x + (xv.y - 0.5f * e.y) * e.y
                     + (xv.z - 0.5f * e.z) * e.z + (xv.w - 0.5f * e.w) * e.w;
#pragma unroll
            for (int m2 = 1; m2 < 16; m2 <<= 1) pp += __shfl_xor(pp, m2, 64);
            bool take = (pp > pbest) || (pp == pbest && cand[c] < cbest);
            pbest = take ? pp : pbest;
            cbest = take ? cand[c] : cbest;
            ebest.x = take ? e.x : ebest.x; ebest.y = take ? e.y : ebest.y;
            ebest.z = take ? e.z : ebest.z; ebest.w = take ? e.w : ebest.w;
        }
        *(float4*)(quant + (size_t)grow * DIM + n * 4) = ebest;
        if (n == 0) idxf[grow] = (float)cbest;
    }
}

extern "C" void kernel_launch(void* const* d_in, const int* in_sizes, int n_in,
                              void* d_out, int out_size, void* d_ws, size_t ws_size,
                              hipStream_t stream) {
    const float* x   = (const float*)d_in[0];   // [65536, 64]
    const float* emb = (const float*)d_in[1];   // [2048, 64]
    float* out   = (float*)d_out;
    float* quant = out;                               // 4194304 floats
    float* idxf  = out + (size_t)N_TOTAL * DIM;       // 65536 floats
    float* flat  = idxf + N_TOTAL;                    // 4194304 floats

    half8* ehp = (half8*)d_ws;                        // 2048*64 f16 frag-major (256 KB)
    float* en  = (float*)((char*)d_ws + (size_t)NEMB * DIM * 2);  // 2048 f32

    prep_kernel<<<64, 256, 0, stream>>>(emb, ehp, en);
    vq_mfma_kernel<<<N_TOTAL / 64, 256, 0, stream>>>(x, emb, (const uint4*)ehp, en,
                                                     quant, idxf, flat);
}